// Round 7
// baseline (128.050 us; speedup 1.0000x reference)
//
#include <hip/hip_runtime.h>

// Problem: B=2, C=256, F*H*W=N=4096, heads=4, dim_head=64, inner=256
#define BATCH 2
#define CCH   256
#define NSEQ  4096
#define NH    4
#define DH    64
#define INNER 256

typedef __attribute__((ext_vector_type(8))) __bf16 bf16x8;
typedef __attribute__((ext_vector_type(4))) float f32x4;
typedef __attribute__((ext_vector_type(8))) unsigned short u16x8;
typedef __attribute__((ext_vector_type(4))) unsigned short u16x4;

// async global->LDS, 16B per lane; LDS dest = wave-uniform base + lane*16
#define GLD16(gsrc, ldst)                                                     \
  __builtin_amdgcn_global_load_lds(                                           \
      (const __attribute__((address_space(1))) unsigned int*)(const void*)(gsrc), \
      (__attribute__((address_space(3))) unsigned int*)(void*)(ldst), 16, 0, 0)

// round-half-up bf16 (inputs finite; <=0.5ulp bias vs RNE, irrelevant here)
static __device__ __forceinline__ unsigned short f2bfr(float f) {
  union { float f; unsigned u; } v; v.f = f;
  return (unsigned short)((v.u + 0x8000u) >> 16);
}
// pack two floats -> bf16 pair (low = f0) via v_perm_b32: 3 VALU ops
static __device__ __forceinline__ unsigned pack2(float f0, float f1) {
  union { float f; unsigned u; } a, b; a.f = f0; b.f = f1;
  return __builtin_amdgcn_perm(b.u + 0x8000u, a.u + 0x8000u, 0x07060302u);
}
// 1-op pack: v_cvt_pk_bf16_f32 (RNE; fine at bf16 tolerance)
static __device__ __forceinline__ unsigned cvtpk(float lo, float hi) {
  unsigned r;
  asm("v_cvt_pk_bf16_f32 %0, %1, %2" : "=v"(r) : "v"(lo), "v"(hi));
  return r;
}
static __device__ __forceinline__ float bf2f(unsigned short u) {
  union { unsigned u; float f; } v; v.u = ((unsigned)u) << 16;
  return v.f;
}
static __device__ __forceinline__ bf16x8 ldb(const unsigned short* p) {
  return *(const bf16x8*)p;
}
static __device__ __forceinline__ f32x4 mm(bf16x8 a, bf16x8 b, f32x4 c) {
  return __builtin_amdgcn_mfma_f32_16x16x32_bf16(a, b, c, 0, 0, 0);
}
// raw v_exp_f32: inputs bounded to |x| <= ~11.6, no denormal fixup needed
static __device__ __forceinline__ float ex2(float x) {
  return __builtin_amdgcn_exp2f(x);
}

// ------ Kernel 1: LN -> xn [b][n][c] bf16  (+ fused fp32->bf16 weight cvt) --
__global__ __launch_bounds__(256) void k_lncvt(const float* __restrict__ x,
                                               const float* __restrict__ gamma,
                                               unsigned short* __restrict__ xn,
                                               const float* __restrict__ wq,
                                               const float* __restrict__ wo,
                                               unsigned short* __restrict__ wqb,
                                               unsigned short* __restrict__ wob) {
  int blk = blockIdx.x;
  if (blk >= 256) {                       // weight convert: 256 blocks
    int t = (blk - 256) * 256 + threadIdx.x;
    int e = t * 4;
    if (e < 768 * 256) {
      float4 v = *(const float4*)(wq + e);
      u16x4 pk = { f2bfr(v.x), f2bfr(v.y), f2bfr(v.z), f2bfr(v.w) };
      *(u16x4*)(wqb + e) = pk;
    } else {
      int e2 = e - 768 * 256;
      float4 v = *(const float4*)(wo + e2);
      u16x4 pk = { f2bfr(v.x), f2bfr(v.y), f2bfr(v.z), f2bfr(v.w) };
      *(u16x4*)(wob + e2) = pk;
    }
    return;
  }
  int b  = blk >> 7;
  int n0 = (blk & 127) * 32;
  int t  = threadIdx.x;
  int nl = t & 31;
  int cg = t >> 5;                 // channel group 0..7 (32 channels each)
  int n  = n0 + nl;
  const float* xp = x + ((size_t)(b * CCH + cg * 32)) * NSEQ + n;
  float vals[32];
  float s = 0.f, s2 = 0.f;
#pragma unroll
  for (int j = 0; j < 32; j++) {
    float v = xp[(size_t)j * NSEQ];
    vals[j] = v; s += v; s2 += v * v;
  }
  __shared__ float rs[8][32], rs2[8][32];
  rs[cg][nl] = s; rs2[cg][nl] = s2;
  __syncthreads();
  float S = 0.f, S2 = 0.f;
#pragma unroll
  for (int g = 0; g < 8; g++) { S += rs[g][nl]; S2 += rs2[g][nl]; }
  float mean = S * (1.f / 256.f);
  float var  = S2 * (1.f / 256.f) - mean * mean;
  float rstd = rsqrtf(var + 1e-5f);
  unsigned short* dst = xn + ((size_t)b * NSEQ + n) * CCH + cg * 32;
#pragma unroll
  for (int j0 = 0; j0 < 32; j0 += 8) {
    u16x8 pk;
#pragma unroll
    for (int j = 0; j < 8; j++)
      pk[j] = f2bfr((vals[j0 + j] - mean) * rstd * gamma[cg * 32 + j0 + j]);
    *(u16x8*)(dst + j0) = pk;
  }
}

// --- Kernel 2: QKV GEMM + fused l2norm, BK=128 (3 barriers total) ----------
__global__ __launch_bounds__(256) void k_qkv(const unsigned short* __restrict__ wqb,
                                             const unsigned short* __restrict__ xn,
                                             unsigned short* __restrict__ qkv,
                                             unsigned short* __restrict__ qt,
                                             unsigned short* __restrict__ ktb) {
  int n0 = blockIdx.x * 64;
  int oi = blockIdx.y;
  int o0 = oi * 64;
  int b  = blockIdx.z;
  __shared__ unsigned short Al[64 * 128];   // [o][k-local] swizzled, 16 KB
  __shared__ unsigned short Bl[64 * 128];   // [n][k-local] swizzled, 16 KB
  int t = threadIdx.x;
  int lane = t & 63, w = t >> 6;
  int c = lane & 15, quad = lane >> 4;
  int wm = w >> 1, wn = w & 1;
  f32x4 acc[2][2] = {};
  int lr = lane >> 4;                       // row within 4-row group
  int lchk = lane & 15;                     // phys chunk (16 chunks/row)
  const unsigned short* apg = wqb + (size_t)o0 * CCH;
  const unsigned short* bpg = xn + ((size_t)b * NSEQ + n0) * CCH;
  for (int kt = 0; kt < 2; kt++) {
    if (kt) __syncthreads();
#pragma unroll
    for (int q = 0; q < 4; q++) {
      int r = w * 16 + q * 4 + lr;
      int srcoff = r * CCH + kt * 128 + ((lchk ^ (r & 7)) * 8);
      GLD16(apg + srcoff, Al + (size_t)(w * 16 + q * 4) * 128);
      GLD16(bpg + srcoff, Bl + (size_t)(w * 16 + q * 4) * 128);
    }
    __syncthreads();
#pragma unroll
    for (int ks = 0; ks < 4; ks++) {
      int ra0 = wm * 32 + c, ra1 = ra0 + 16;
      int rb0 = wn * 32 + c, rb1 = rb0 + 16;
      bf16x8 a0 = ldb(&Al[ra0 * 128 + (((ks * 4 + quad) ^ (ra0 & 7)) * 8)]);
      bf16x8 a1 = ldb(&Al[ra1 * 128 + (((ks * 4 + quad) ^ (ra1 & 7)) * 8)]);
      bf16x8 b0 = ldb(&Bl[rb0 * 128 + (((ks * 4 + quad) ^ (rb0 & 7)) * 8)]);
      bf16x8 b1 = ldb(&Bl[rb1 * 128 + (((ks * 4 + quad) ^ (rb1 & 7)) * 8)]);
      acc[0][0] = mm(a0, b0, acc[0][0]);
      acc[0][1] = mm(a0, b1, acc[0][1]);
      acc[1][0] = mm(a1, b0, acc[1][0]);
      acc[1][1] = mm(a1, b1, acc[1][1]);
    }
  }
  if (oi < 8) {
    float* sq = (float*)Al;                 // reuse Al after final reads
    float s0 = 0.f, s1 = 0.f;
#pragma unroll
    for (int i = 0; i < 2; i++)
#pragma unroll
      for (int rr = 0; rr < 4; rr++) {
        s0 += acc[i][0][rr] * acc[i][0][rr];
        s1 += acc[i][1][rr] * acc[i][1][rr];
      }
    s0 += __shfl_xor(s0, 16); s0 += __shfl_xor(s0, 32);
    s1 += __shfl_xor(s1, 16); s1 += __shfl_xor(s1, 32);
    __syncthreads();
    if (quad == 0) {
      sq[wm * 64 + wn * 32 + c]      = s0;
      sq[wm * 64 + wn * 32 + 16 + c] = s1;
    }
    __syncthreads();
    float r0 = rsqrtf(sq[wn * 32 + c]      + sq[64 + wn * 32 + c]      + 1e-12f);
    float r1 = rsqrtf(sq[wn * 32 + 16 + c] + sq[64 + wn * 32 + 16 + c] + 1e-12f);
    if (oi < 4) { r0 *= 11.541560327111707f; r1 *= 11.541560327111707f; } // 8*log2e
    int h = oi & 3;
    unsigned short* base = (oi < 4 ? qt : ktb) + ((size_t)(b * NH + h) * NSEQ) * DH;
#pragma unroll
    for (int i = 0; i < 2; i++)
#pragma unroll
      for (int j = 0; j < 2; j++) {
        float rsc = j ? r1 : r0;
        int n = n0 + wn * 32 + j * 16 + c;
        int d = wm * 32 + i * 16 + quad * 4;
        uint2 pk = { pack2(acc[i][j][0] * rsc, acc[i][j][1] * rsc),
                     pack2(acc[i][j][2] * rsc, acc[i][j][3] * rsc) };
        *(uint2*)(base + (size_t)n * DH + d) = pk;
      }
  } else {
#pragma unroll
    for (int i = 0; i < 2; i++)
#pragma unroll
      for (int j = 0; j < 2; j++)
#pragma unroll
        for (int rr = 0; rr < 4; rr++) {
          int o = o0 + wm * 32 + i * 16 + quad * 4 + rr;
          int n = n0 + wn * 32 + j * 16 + c;
          qkv[((size_t)b * 768 + o) * NSEQ + n] = f2bfr(acc[i][j][rr]);
        }
  }
}

// ------ Kernel 3: flash attention, Q-tile 256, T15 deferred-PV pipeline ----
// Iter i computes QK(i)->pNew while PV(i-1) (independent, from pOld) is
// interleaved between the QK clusters -> matrix pipe fed during exp2, VALU
// during PV. P double-buffered in registers (pA/pB, static via unroll-2).
// V(i) staged at iter i (read at i+1) so 2 LDS buffers suffice (no clash
// with deferred read). K dbuf as before. One __syncthreads per iter.
__global__ __launch_bounds__(256, 2) void k_attn(
    const unsigned short* __restrict__ qt,
    const unsigned short* __restrict__ ktb,
    const unsigned short* __restrict__ qkv,
    unsigned short* __restrict__ opart,
    float* __restrict__ lpart,
    int S, int kvlen) {
  int i0 = blockIdx.x * 256;
  int h  = blockIdx.y;
  int bz = blockIdx.z;
  int b  = bz / S, s = bz % S;
  __shared__ unsigned short Kl[2][64 * 64];  // [j][d] f-swizzled, 2x8 KB
  __shared__ unsigned short Vl[2][64 * 64];  // [d][j] swizzled, 2x8 KB
  int t = threadIdx.x;
  int lane = t & 63, w = t >> 6;
  int c = lane & 15, quad = lane >> 4;

  const unsigned short* qbase = qt  + ((size_t)(b * NH + h) * NSEQ) * DH;
  const unsigned short* kbase = ktb + ((size_t)(b * NH + h) * NSEQ) * DH;
  const unsigned short* vbase = qkv + ((size_t)b * 768 + 512 + h * 64) * NSEQ;

  // Q fragments straight from global (one-time, L2-served); 4 sets of 16 rows
  bf16x8 qa[4], qb[4];
#pragma unroll
  for (int ss = 0; ss < 4; ss++) {
    const unsigned short* qp =
        qbase + (size_t)(i0 + w * 64 + ss * 16 + c) * DH + quad * 8;
    qa[ss] = ldb(qp); qb[ss] = ldb(qp + 32);
  }

  u16x8 onesu;
#pragma unroll
  for (int j = 0; j < 8; j++) onesu[j] = 0x3F80;               // bf16 1.0
  bf16x8 ones = *(bf16x8*)&onesu;

  f32x4 acc[4][4] = {};    // [q-set][dt]
  f32x4 accl[4]  = {};     // [q-set] row-sum

  // staging: lane covers row w*16 + {0,8} + (lane>>3), phys chunk lane&7
  int slr = lane >> 3, slc = lane & 7;
  int ssw_v  = (slc ^ slr) * 8;             // V source swizzle (f_v(r)=r&7)
  int ssw_k1 = (slc ^ (slr & 3)) * 8;       // K rows u=0..7  (f=u&3)
  int ssw_k2 = ssw_k1 ^ 32;                 // K rows u=8..15 (f=(u&3)|4)
  const unsigned short* kp = kbase + (size_t)(s * kvlen + w * 16 + slr) * DH;
  const unsigned short* vp = vbase + (size_t)(w * 16 + slr) * NSEQ + s * kvlen + ssw_v;
  int sw0 = (quad ^ (c & 7)) * 8;           // V ds_read swizzled chunk offsets
  int sw1 = sw0 ^ 32;
  // K permuted read: row sigma_t(c), f(sigma_t(c)) = (c&3)|(((c>>2)&1)<<2)
  int fK    = (c & 3) | (((c >> 2) & 1) << 2);
  int swk0  = (quad ^ fK) * 8;
  int swk1  = swk0 ^ 32;
  int krow0 = (c >> 2) * 8 + (c & 3);

  int nIt = kvlen / 64;                     // 16/32/64 — always even
  // prologue: stage K(0) only (V(0) staged inside iter 0)
  GLD16(kp + ssw_k1,          &Kl[0][(w * 16)     * 64]);
  GLD16(kp + 8 * DH + ssw_k2, &Kl[0][(w * 16 + 8) * 64]);
  kp += 64 * DH;

  union U4 { unsigned u[4]; bf16x8 v; };
  U4 pA0[4], pA1[4], pB0[4], pB1[4];

// one q-set's QK (8 MFMA) + exp2 + pack into its PV A-fragments
#define QKSET(qA, qB, P0, P1)                                                 \
  {                                                                           \
    f32x4 z0 = {}, z1 = {}, z2 = {}, z3 = {};                                 \
    __builtin_amdgcn_s_setprio(1);                                            \
    z0 = mm(k00, qA, z0); z0 = mm(k01, qB, z0);                               \
    z1 = mm(k10, qA, z1); z1 = mm(k11, qB, z1);                               \
    z2 = mm(k20, qA, z2); z2 = mm(k21, qB, z2);                               \
    z3 = mm(k30, qA, z3); z3 = mm(k31, qB, z3);                               \
    __builtin_amdgcn_s_setprio(0);                                            \
    P0.u[0] = cvtpk(ex2(z0[0]), ex2(z0[1]));                                  \
    P0.u[1] = cvtpk(ex2(z0[2]), ex2(z0[3]));                                  \
    P0.u[2] = cvtpk(ex2(z1[0]), ex2(z1[1]));                                  \
    P0.u[3] = cvtpk(ex2(z1[2]), ex2(z1[3]));                                  \
    P1.u[0] = cvtpk(ex2(z2[0]), ex2(z2[1]));                                  \
    P1.u[1] = cvtpk(ex2(z2[2]), ex2(z2[3]));                                  \
    P1.u[2] = cvtpk(ex2(z3[0]), ex2(z3[1]));                                  \
    P1.u[3] = cvtpk(ex2(z3[2]), ex2(z3[3]));                                  \
  }

// deferred PV for one dt: V(prev tile) x all 4 q-sets of old P
#define PVD(dt, Vb, PO0, PO1)                                                 \
  {                                                                           \
    bf16x8 v0 = ldb(&Vb[((dt) * 16 + c) * 64 + sw0]);                         \
    bf16x8 v1 = ldb(&Vb[((dt) * 16 + c) * 64 + sw1]);                         \
    __builtin_amdgcn_s_setprio(1);                                            \
    acc[0][dt] = mm(PO0[0].v, v0, acc[0][dt]);                                \
    acc[0][dt] = mm(PO1[0].v, v1, acc[0][dt]);                                \
    acc[1][dt] = mm(PO0[1].v, v0, acc[1][dt]);                                \
    acc[1][dt] = mm(PO1[1].v, v1, acc[1][dt]);                                \
    acc[2][dt] = mm(PO0[2].v, v0, acc[2][dt]);                                \
    acc[2][dt] = mm(PO1[2].v, v1, acc[2][dt]);                                \
    acc[3][dt] = mm(PO0[3].v, v0, acc[3][dt]);                                \
    acc[3][dt] = mm(PO1[3].v, v1, acc[3][dt]);                                \
    __builtin_amdgcn_s_setprio(0);                                            \
  }

#define ACCL(PO0, PO1)                                                        \
  __builtin_amdgcn_s_setprio(1);                                              \
  accl[0] = mm(PO0[0].v, ones, accl[0]); accl[0] = mm(PO1[0].v, ones, accl[0]); \
  accl[1] = mm(PO0[1].v, ones, accl[1]); accl[1] = mm(PO1[1].v, ones, accl[1]); \
  accl[2] = mm(PO0[2].v, ones, accl[2]); accl[2] = mm(PO1[2].v, ones, accl[2]); \
  accl[3] = mm(PO0[3].v, ones, accl[3]); accl[3] = mm(PO1[3].v, ones, accl[3]); \
  __builtin_amdgcn_s_setprio(0);

// one pipeline step: QK(IT)->PN, PV(IT-1) from PO, stage K(IT+1) + V(IT)
#define ITER(IT, PN0, PN1, PO0, PO1, DO_PV)                                   \
  {                                                                           \
    __syncthreads(); /* drains K(IT) + V(IT-1) staging; prior reads done */   \
    if ((IT) + 1 < nIt) {                                                     \
      unsigned short* kd = &Kl[((IT) + 1) & 1][0];                            \
      GLD16(kp + ssw_k1,          kd + (w * 16) * 64);                        \
      GLD16(kp + 8 * DH + ssw_k2, kd + (w * 16 + 8) * 64);                    \
      kp += 64 * DH;                                                          \
    }                                                                         \
    {                                                                         \
      unsigned short* vd = &Vl[(IT) & 1][0];                                  \
      GLD16(vp,            vd + (w * 16) * 64);                               \
      GLD16(vp + 8 * NSEQ, vd + (w * 16 + 8) * 64);                           \
      vp += 64;                                                               \
    }                                                                         \
    const unsigned short* Kb = &Kl[(IT) & 1][0];                              \
    const unsigned short* Vb = &Vl[((IT) + 1) & 1][0]; /* == (IT-1)&1 */      \
    bf16x8 k00 = ldb(&Kb[(krow0)      * 64 + swk0]);                          \
    bf16x8 k01 = ldb(&Kb[(krow0)      * 64 + swk1]);                          \
    bf16x8 k10 = ldb(&Kb[(krow0 + 4)  * 64 + swk0]);                          \
    bf16x8 k11 = ldb(&Kb[(krow0 + 4)  * 64 + swk1]);                          \
    bf16x8 k20 = ldb(&Kb[(krow0 + 32) * 64 + swk0]);                          \
    bf16x8 k21 = ldb(&Kb[(krow0 + 32) * 64 + swk1]);                          \
    bf16x8 k30 = ldb(&Kb[(krow0 + 36) * 64 + swk0]);                          \
    bf16x8 k31 = ldb(&Kb[(krow0 + 36) * 64 + swk1]);                          \
    QKSET(qa[0], qb[0], PN0[0], PN1[0]);                                      \
    if (DO_PV) PVD(0, Vb, PO0, PO1);                                          \
    QKSET(qa[1], qb[1], PN0[1], PN1[1]);                                      \
    if (DO_PV) PVD(1, Vb, PO0, PO1);                                          \
    QKSET(qa[2], qb[2], PN0[2], PN1[2]);                                      \
    if (DO_PV) PVD(2, Vb, PO0, PO1);                                          \
    QKSET(qa[3], qb[3], PN0[3], PN1[3]);                                      \
    if (DO_PV) PVD(3, Vb, PO0, PO1);                                          \
    if (DO_PV) { ACCL(PO0, PO1); }                                            \
  }

  for (int itp = 0; itp < nIt / 2; ++itp) {
    int it0 = itp * 2;
    ITER(it0,     pA0, pA1, pB0, pB1, (itp > 0));   // even: QK->pA, PV from pB
    ITER(it0 + 1, pB0, pB1, pA0, pA1, 1);           // odd:  QK->pB, PV from pA
  }
  // epilogue: PV of the last tile (P in pB, V in Vl[(nIt-1)&1] == Vl[1])
  __syncthreads();
  {
    const unsigned short* Vb = &Vl[1][0];
    PVD(0, Vb, pB0, pB1);
    PVD(1, Vb, pB0, pB1);
    PVD(2, Vb, pB0, pB1);
    PVD(3, Vb, pB0, pB1);
    ACCL(pB0, pB1);
  }
#undef ITER
#undef ACCL
#undef PVD
#undef QKSET

  size_t rb = ((size_t)(b * NH + h) * S + s) * NSEQ + i0 + w * 64;
#pragma unroll
  for (int ss = 0; ss < 4; ss++) {
    size_t rbs = rb + ss * 16;
    if (c == 0) {
#pragma unroll
      for (int rr = 0; rr < 4; rr++)
        lpart[rbs + quad * 4 + rr] = accl[ss][rr];
    }
#pragma unroll
    for (int rr = 0; rr < 4; rr++)
#pragma unroll
      for (int dt = 0; dt < 4; dt++)
        opart[(rbs + quad * 4 + rr) * 64 + dt * 16 + c] = f2bfr(acc[ss][dt][rr]);
  }
}

// ------ Kernel 4: out-proj + residual, with FUSED split-KV merge -----------
// B-tile built inline from opart/lpart (coalesced 16B/lane reads, bf16 pack,
// swizzled ds_write) — replaces the separate k_merge kernel and the ao
// roundtrip. A (weights) staged full-K via GLD16; one barrier; 8 K-steps.
__global__ __launch_bounds__(256) void k_out(const unsigned short* __restrict__ wob,
                                             const unsigned short* __restrict__ opart,
                                             const float* __restrict__ lpart,
                                             const float* __restrict__ x,
                                             float* __restrict__ out, int S) {
  int n0 = blockIdx.x * 64;
  int o0 = blockIdx.y * 64;
  int b  = blockIdx.z;
  __shared__ unsigned short Al[64 * 256];   // 32 KB, [o][k] swizzled
  __shared__ unsigned short Bl[64 * 256];   // 32 KB, [n][k] swizzled
  int t = threadIdx.x;
  int lane = t & 63, w = t >> 6;
  int c = lane & 15, quad = lane >> 4;
  int wm = w >> 1, wn = w & 1;
  // --- A stage: full-K via GLD16 ---
  int lr2 = lane >> 5, lch = lane & 31;
  const unsigned short* apg = wob + (size_t)o0 * INNER;
#pragma unroll
  for (int q = 0; q < 8; q++) {
    int r = w * 16 + q * 2 + lr2;
    int srcoff = r * INNER + ((lch ^ (r & 7)) * 8);
    GLD16(apg + srcoff, Al + (size_t)(w * 16 + q * 2) * 256);
  }
  // --- B stage: merge opart/lpart -> bf16 -> swizzled Bl ---
  int n_l = t >> 2;                 // 0..63: row of B tile
  int seg = t & 3;                  // 16-elem segment within a head
#pragma unroll
  for (int hh = 0; hh < 4; hh++) {
    float l = 0.f;
    float o[16];
#pragma unroll
    for (int j = 0; j < 16; j++) o[j] = 0.f;
    for (int s = 0; s < S; s++) {
      size_t rbm = ((size_t)(b * NH + hh) * S + s) * NSEQ + n0 + n_l;
      l += lpart[rbm];
      const unsigned short* p = opart + rbm * 64 + seg * 16;
      u16x8 v0 = *(const u16x8*)p;
      u16x8 v1 = *(const u16x8*)(p + 8);
#pragma unroll
      for (int j = 0; j < 8; j++) {
        o[j]     += bf2f(v0[j]);
        o[8 + j] += bf2f(v1[j]);
      }
    }
    float inv = 1.f / l;
    int cc = hh * 8 + seg * 2;      // 8-elem chunk index (0..31)
    uint4 pkA = { pack2(o[0] * inv,  o[1] * inv),  pack2(o[2] * inv,  o[3] * inv),
                  pack2(o[4] * inv,  o[5] * inv),  pack2(o[6] * inv,  o[7] * inv) };
    uint4 pkB = { pack2(o[8] * inv,  o[9] * inv),  pack2(o[10] * inv, o[11] * inv),
                  pack2(o[12] * inv, o[13] * inv), pack2(o[14] * inv, o[15] * inv) };
    *(uint4*)&Bl[n_l * 256 + (((cc)     ^ (n_l & 7)) * 8)] = pkA;
    *(uint4*)&Bl[n_l * 256 + (((cc + 1) ^ (n_l & 7)) * 8)] = pkB;
  }
  __syncthreads();
  // --- GEMM: full K = 256, 8 steps ---
  f32x4 acc[2][2] = {};
#pragma unroll
  for (int ks = 0; ks < 8; ks++) {
    int ra0 = wm * 32 + c, ra1 = ra0 + 16;
    int rb0 = wn * 32 + c, rb1 = rb0 + 16;
    bf16x8 a0 = ldb(&Al[ra0 * 256 + (((ks * 4 + quad) ^ (ra0 & 7)) * 8)]);
    bf16x8 a1 = ldb(&Al[ra1 * 256 + (((ks * 4 + quad) ^ (ra1 & 7)) * 8)]);
    bf16x8 b0 = ldb(&Bl[rb0 * 256 + (((ks * 4 + quad) ^ (rb0 & 7)) * 8)]);
    bf16x8 b1 = ldb(&Bl[rb1 * 256 + (((ks * 4 + quad) ^ (rb1 & 7)) * 8)]);
    acc[0][0] = mm(a0, b0, acc[0][0]);
    acc[0][1] = mm(a0, b1, acc[0][1]);
    acc[1][0] = mm(a1, b0, acc[1][0]);
    acc[1][1] = mm(a1, b1, acc[1][1]);
  }
#pragma unroll
  for (int i = 0; i < 2; i++)
#pragma unroll
    for (int j = 0; j < 2; j++)
#pragma unroll
      for (int rr = 0; rr < 4; rr++) {
        int o = o0 + wm * 32 + i * 16 + quad * 4 + rr;
        int n = n0 + wn * 32 + j * 16 + c;
        size_t idx = ((size_t)b * CCH + o) * NSEQ + n;
        out[idx] = acc[i][j][rr] + x[idx];
      }
}

extern "C" void kernel_launch(void* const* d_in, const int* in_sizes, int n_in,
                              void* d_out, int out_size, void* d_ws, size_t ws_size,
                              hipStream_t stream) {
  const float* x     = (const float*)d_in[0];
  const float* gamma = (const float*)d_in[1];
  const float* wq    = (const float*)d_in[2];
  const float* wo    = (const float*)d_in[3];
  float* out = (float*)d_out;

  const size_t MB = 1u << 20;
  char* ws = (char*)d_ws;
  // ws layout:
  unsigned short* xn  = (unsigned short*)(ws + 4 * MB);        // [4,8)  bf16 [B][N][256]
  unsigned short* qkv = (unsigned short*)(ws + 8 * MB);        // [8,20) bf16 [B][768][N] (v region used)
  unsigned short* wqb = (unsigned short*)(ws + 20 * MB);       // 384 KB
  unsigned short* wob = (unsigned short*)(ws + 20 * MB + 512 * 1024); // 128 KB
  unsigned short* qt  = (unsigned short*)(ws + 21 * MB);       // [21,25) bf16 [B][H][N][D]
  unsigned short* ktb = (unsigned short*)(ws + 25 * MB);       // [25,29) bf16 [B][H][N][D]
  unsigned short* opart = (unsigned short*)(ws + 29 * MB);     // S*B*H*N*64 bf16
  int S;
  if (ws_size >= 48 * MB) S = 4;
  else if (ws_size >= 40 * MB) S = 2;
  else S = 1;
  size_t opart_bytes = (size_t)S * BATCH * NH * NSEQ * DH * 2;
  float* lpart = (float*)(ws + 29 * MB + opart_bytes);
  int kvlen = NSEQ / S;

  k_lncvt<<<dim3(512),          256, 0, stream>>>(x, gamma, xn, wq, wo, wqb, wob);
  k_qkv  <<<dim3(64, 12, 2),    256, 0, stream>>>(wqb, xn, qkv, qt, ktb);
  k_attn <<<dim3(16, 4, 2 * S), 256, 0, stream>>>(qt, ktb, qkv, opart,
                                                  lpart, S, kvlen);
  k_out  <<<dim3(64, 4, 2),     256, 0, stream>>>(wob, opart, lpart, x, out, S);
}

// Round 8
// 122.667 us; speedup vs baseline: 1.0439x; 1.0439x over previous
//
#include <hip/hip_runtime.h>

// Problem: B=2, C=256, F*H*W=N=4096, heads=4, dim_head=64, inner=256
#define BATCH 2
#define CCH   256
#define NSEQ  4096
#define NH    4
#define DH    64
#define INNER 256

typedef __attribute__((ext_vector_type(8))) __bf16 bf16x8;
typedef __attribute__((ext_vector_type(4))) float f32x4;
typedef __attribute__((ext_vector_type(8))) unsigned short u16x8;
typedef __attribute__((ext_vector_type(4))) unsigned short u16x4;

// async global->LDS, 16B per lane; LDS dest = wave-uniform base + lane*16
#define GLD16(gsrc, ldst)                                                     \
  __builtin_amdgcn_global_load_lds(                                           \
      (const __attribute__((address_space(1))) unsigned int*)(const void*)(gsrc), \
      (__attribute__((address_space(3))) unsigned int*)(void*)(ldst), 16, 0, 0)

// round-half-up bf16 (inputs finite; <=0.5ulp bias vs RNE, irrelevant here)
static __device__ __forceinline__ unsigned short f2bfr(float f) {
  union { float f; unsigned u; } v; v.f = f;
  return (unsigned short)((v.u + 0x8000u) >> 16);
}
// pack two floats -> bf16 pair (low = f0) via v_perm_b32: 3 VALU ops
static __device__ __forceinline__ unsigned pack2(float f0, float f1) {
  union { float f; unsigned u; } a, b; a.f = f0; b.f = f1;
  return __builtin_amdgcn_perm(b.u + 0x8000u, a.u + 0x8000u, 0x07060302u);
}
// 1-op pack: v_cvt_pk_bf16_f32 (RNE; fine at bf16 tolerance)
static __device__ __forceinline__ unsigned cvtpk(float lo, float hi) {
  unsigned r;
  asm("v_cvt_pk_bf16_f32 %0, %1, %2" : "=v"(r) : "v"(lo), "v"(hi));
  return r;
}
static __device__ __forceinline__ float bf2f(unsigned short u) {
  union { unsigned u; float f; } v; v.u = ((unsigned)u) << 16;
  return v.f;
}
static __device__ __forceinline__ bf16x8 ldb(const unsigned short* p) {
  return *(const bf16x8*)p;
}
static __device__ __forceinline__ f32x4 mm(bf16x8 a, bf16x8 b, f32x4 c) {
  return __builtin_amdgcn_mfma_f32_16x16x32_bf16(a, b, c, 0, 0, 0);
}
// raw v_exp_f32: inputs bounded to |x| <= ~11.6, no denormal fixup needed
static __device__ __forceinline__ float ex2(float x) {
  return __builtin_amdgcn_exp2f(x);
}

// ------ Kernel 1: LN -> xn [b][n][c] bf16  (+ fused fp32->bf16 weight cvt) --
__global__ __launch_bounds__(256) void k_lncvt(const float* __restrict__ x,
                                               const float* __restrict__ gamma,
                                               unsigned short* __restrict__ xn,
                                               const float* __restrict__ wq,
                                               const float* __restrict__ wo,
                                               unsigned short* __restrict__ wqb,
                                               unsigned short* __restrict__ wob) {
  int blk = blockIdx.x;
  if (blk >= 256) {                       // weight convert: 256 blocks
    int t = (blk - 256) * 256 + threadIdx.x;
    int e = t * 4;
    if (e < 768 * 256) {
      float4 v = *(const float4*)(wq + e);
      u16x4 pk = { f2bfr(v.x), f2bfr(v.y), f2bfr(v.z), f2bfr(v.w) };
      *(u16x4*)(wqb + e) = pk;
    } else {
      int e2 = e - 768 * 256;
      float4 v = *(const float4*)(wo + e2);
      u16x4 pk = { f2bfr(v.x), f2bfr(v.y), f2bfr(v.z), f2bfr(v.w) };
      *(u16x4*)(wob + e2) = pk;
    }
    return;
  }
  int b  = blk >> 7;
  int n0 = (blk & 127) * 32;
  int t  = threadIdx.x;
  int nl = t & 31;
  int cg = t >> 5;                 // channel group 0..7 (32 channels each)
  int n  = n0 + nl;
  const float* xp = x + ((size_t)(b * CCH + cg * 32)) * NSEQ + n;
  float vals[32];
  float s = 0.f, s2 = 0.f;
#pragma unroll
  for (int j = 0; j < 32; j++) {
    float v = xp[(size_t)j * NSEQ];
    vals[j] = v; s += v; s2 += v * v;
  }
  __shared__ float rs[8][32], rs2[8][32];
  rs[cg][nl] = s; rs2[cg][nl] = s2;
  __syncthreads();
  float S = 0.f, S2 = 0.f;
#pragma unroll
  for (int g = 0; g < 8; g++) { S += rs[g][nl]; S2 += rs2[g][nl]; }
  float mean = S * (1.f / 256.f);
  float var  = S2 * (1.f / 256.f) - mean * mean;
  float rstd = rsqrtf(var + 1e-5f);
  unsigned short* dst = xn + ((size_t)b * NSEQ + n) * CCH + cg * 32;
#pragma unroll
  for (int j0 = 0; j0 < 32; j0 += 8) {
    u16x8 pk;
#pragma unroll
    for (int j = 0; j < 8; j++)
      pk[j] = f2bfr((vals[j0 + j] - mean) * rstd * gamma[cg * 32 + j0 + j]);
    *(u16x8*)(dst + j0) = pk;
  }
}

// --- Kernel 2: QKV GEMM + fused l2norm, BK=128 (3 barriers total) ----------
__global__ __launch_bounds__(256) void k_qkv(const unsigned short* __restrict__ wqb,
                                             const unsigned short* __restrict__ xn,
                                             unsigned short* __restrict__ qkv,
                                             unsigned short* __restrict__ qt,
                                             unsigned short* __restrict__ ktb) {
  int n0 = blockIdx.x * 64;
  int oi = blockIdx.y;
  int o0 = oi * 64;
  int b  = blockIdx.z;
  __shared__ unsigned short Al[64 * 128];   // [o][k-local] swizzled, 16 KB
  __shared__ unsigned short Bl[64 * 128];   // [n][k-local] swizzled, 16 KB
  int t = threadIdx.x;
  int lane = t & 63, w = t >> 6;
  int c = lane & 15, quad = lane >> 4;
  int wm = w >> 1, wn = w & 1;
  f32x4 acc[2][2] = {};
  int lr = lane >> 4;                       // row within 4-row group
  int lchk = lane & 15;                     // phys chunk (16 chunks/row)
  const unsigned short* apg = wqb + (size_t)o0 * CCH;
  const unsigned short* bpg = xn + ((size_t)b * NSEQ + n0) * CCH;
  for (int kt = 0; kt < 2; kt++) {
    if (kt) __syncthreads();
#pragma unroll
    for (int q = 0; q < 4; q++) {
      int r = w * 16 + q * 4 + lr;
      int srcoff = r * CCH + kt * 128 + ((lchk ^ (r & 7)) * 8);
      GLD16(apg + srcoff, Al + (size_t)(w * 16 + q * 4) * 128);
      GLD16(bpg + srcoff, Bl + (size_t)(w * 16 + q * 4) * 128);
    }
    __syncthreads();
#pragma unroll
    for (int ks = 0; ks < 4; ks++) {
      int ra0 = wm * 32 + c, ra1 = ra0 + 16;
      int rb0 = wn * 32 + c, rb1 = rb0 + 16;
      bf16x8 a0 = ldb(&Al[ra0 * 128 + (((ks * 4 + quad) ^ (ra0 & 7)) * 8)]);
      bf16x8 a1 = ldb(&Al[ra1 * 128 + (((ks * 4 + quad) ^ (ra1 & 7)) * 8)]);
      bf16x8 b0 = ldb(&Bl[rb0 * 128 + (((ks * 4 + quad) ^ (rb0 & 7)) * 8)]);
      bf16x8 b1 = ldb(&Bl[rb1 * 128 + (((ks * 4 + quad) ^ (rb1 & 7)) * 8)]);
      acc[0][0] = mm(a0, b0, acc[0][0]);
      acc[0][1] = mm(a0, b1, acc[0][1]);
      acc[1][0] = mm(a1, b0, acc[1][0]);
      acc[1][1] = mm(a1, b1, acc[1][1]);
    }
  }
  if (oi < 8) {
    float* sq = (float*)Al;                 // reuse Al after final reads
    float s0 = 0.f, s1 = 0.f;
#pragma unroll
    for (int i = 0; i < 2; i++)
#pragma unroll
      for (int rr = 0; rr < 4; rr++) {
        s0 += acc[i][0][rr] * acc[i][0][rr];
        s1 += acc[i][1][rr] * acc[i][1][rr];
      }
    s0 += __shfl_xor(s0, 16); s0 += __shfl_xor(s0, 32);
    s1 += __shfl_xor(s1, 16); s1 += __shfl_xor(s1, 32);
    __syncthreads();
    if (quad == 0) {
      sq[wm * 64 + wn * 32 + c]      = s0;
      sq[wm * 64 + wn * 32 + 16 + c] = s1;
    }
    __syncthreads();
    float r0 = rsqrtf(sq[wn * 32 + c]      + sq[64 + wn * 32 + c]      + 1e-12f);
    float r1 = rsqrtf(sq[wn * 32 + 16 + c] + sq[64 + wn * 32 + 16 + c] + 1e-12f);
    if (oi < 4) { r0 *= 11.541560327111707f; r1 *= 11.541560327111707f; } // 8*log2e
    int h = oi & 3;
    unsigned short* base = (oi < 4 ? qt : ktb) + ((size_t)(b * NH + h) * NSEQ) * DH;
#pragma unroll
    for (int i = 0; i < 2; i++)
#pragma unroll
      for (int j = 0; j < 2; j++) {
        float rsc = j ? r1 : r0;
        int n = n0 + wn * 32 + j * 16 + c;
        int d = wm * 32 + i * 16 + quad * 4;
        uint2 pk = { pack2(acc[i][j][0] * rsc, acc[i][j][1] * rsc),
                     pack2(acc[i][j][2] * rsc, acc[i][j][3] * rsc) };
        *(uint2*)(base + (size_t)n * DH + d) = pk;
      }
  } else {
#pragma unroll
    for (int i = 0; i < 2; i++)
#pragma unroll
      for (int j = 0; j < 2; j++)
#pragma unroll
        for (int rr = 0; rr < 4; rr++) {
          int o = o0 + wm * 32 + i * 16 + quad * 4 + rr;
          int n = n0 + wn * 32 + j * 16 + c;
          qkv[((size_t)b * 768 + o) * NSEQ + n] = f2bfr(acc[i][j][rr]);
        }
  }
}

// ------ Kernel 3: flash attention, Q-tile 256 (4 q-sets/wave) --------------
// R8 experiment: IDENTICAL to the R6 structure (best-known, 42.1us) with all
// s_setprio brackets REMOVED. Theory: setprio has unspecified side effects,
// so LLVM cannot migrate instructions across it — the 9 bracket pairs/iter
// pinned QK-MFMA / exp2-VALU / PV-MFMA into serialized program-order islands
// (matrix pipe measured 44% busy, 6300cy/iter vs 2800cy MFMA work). With the
// fences gone the scheduler can overlap exp2 of set s with MFMAs of set s+1
// and PV. K/V GLD16 double-buffered; P in registers via row-permuted K.
__global__ __launch_bounds__(256, 2) void k_attn(
    const unsigned short* __restrict__ qt,
    const unsigned short* __restrict__ ktb,
    const unsigned short* __restrict__ qkv,
    unsigned short* __restrict__ opart,
    float* __restrict__ lpart,
    int S, int kvlen) {
  int i0 = blockIdx.x * 256;
  int h  = blockIdx.y;
  int bz = blockIdx.z;
  int b  = bz / S, s = bz % S;
  __shared__ unsigned short Kl[2][64 * 64];  // [j][d] f-swizzled, 2x8 KB
  __shared__ unsigned short Vl[2][64 * 64];  // [d][j] swizzled, 2x8 KB
  int t = threadIdx.x;
  int lane = t & 63, w = t >> 6;
  int c = lane & 15, quad = lane >> 4;

  const unsigned short* qbase = qt  + ((size_t)(b * NH + h) * NSEQ) * DH;
  const unsigned short* kbase = ktb + ((size_t)(b * NH + h) * NSEQ) * DH;
  const unsigned short* vbase = qkv + ((size_t)b * 768 + 512 + h * 64) * NSEQ;

  // Q fragments straight from global (one-time, L2-served); 4 sets of 16 rows
  bf16x8 qa[4], qb[4];
#pragma unroll
  for (int ss = 0; ss < 4; ss++) {
    const unsigned short* qp =
        qbase + (size_t)(i0 + w * 64 + ss * 16 + c) * DH + quad * 8;
    qa[ss] = ldb(qp); qb[ss] = ldb(qp + 32);
  }

  u16x8 onesu;
#pragma unroll
  for (int j = 0; j < 8; j++) onesu[j] = 0x3F80;               // bf16 1.0
  bf16x8 ones = *(bf16x8*)&onesu;

  f32x4 acc[4][4] = {};    // [q-set][dt]
  f32x4 accl[4]  = {};     // [q-set] row-sum

  // staging: lane covers row w*16 + {0,8} + (lane>>3), phys chunk lane&7
  int slr = lane >> 3, slc = lane & 7;
  int ssw_v  = (slc ^ slr) * 8;             // V source swizzle (f_v(r)=r&7)
  int ssw_k1 = (slc ^ (slr & 3)) * 8;       // K rows u=0..7  (f=u&3)
  int ssw_k2 = ssw_k1 ^ 32;                 // K rows u=8..15 (f=(u&3)|4)
  const unsigned short* kp = kbase + (size_t)(s * kvlen + w * 16 + slr) * DH;
  const unsigned short* vp = vbase + (size_t)(w * 16 + slr) * NSEQ + s * kvlen + ssw_v;
  int sw0 = (quad ^ (c & 7)) * 8;           // V ds_read swizzled chunk offsets
  int sw1 = sw0 ^ 32;
  // K permuted read: row sigma_t(c), f(sigma_t(c)) = (c&3)|(((c>>2)&1)<<2)
  int fK    = (c & 3) | (((c >> 2) & 1) << 2);
  int swk0  = (quad ^ fK) * 8;
  int swk1  = swk0 ^ 32;
  int krow0 = (c >> 2) * 8 + (c & 3);

  int nIt = kvlen / 64;
  // prologue: stage K(0), V(0) into buffer 0
  GLD16(kp + ssw_k1,          &Kl[0][(w * 16)     * 64]);
  GLD16(kp + 8 * DH + ssw_k2, &Kl[0][(w * 16 + 8) * 64]);
  GLD16(vp,                   &Vl[0][(w * 16)     * 64]);
  GLD16(vp + 8 * NSEQ,        &Vl[0][(w * 16 + 8) * 64]);
  kp += 64 * DH; vp += 64;

  union U4 { unsigned u[4]; bf16x8 v; };
  U4 p0[4], p1[4];

// one q-set's QK (8 MFMA) + exp2 + pack into its PV A-fragments
#define QKSET(qA, qB, P0, P1)                                                 \
  {                                                                           \
    f32x4 z0 = {}, z1 = {}, z2 = {}, z3 = {};                                 \
    z0 = mm(k00, qA, z0); z0 = mm(k01, qB, z0);                               \
    z1 = mm(k10, qA, z1); z1 = mm(k11, qB, z1);                               \
    z2 = mm(k20, qA, z2); z2 = mm(k21, qB, z2);                               \
    z3 = mm(k30, qA, z3); z3 = mm(k31, qB, z3);                               \
    P0.u[0] = cvtpk(ex2(z0[0]), ex2(z0[1]));                                  \
    P0.u[1] = cvtpk(ex2(z0[2]), ex2(z0[3]));                                  \
    P0.u[2] = cvtpk(ex2(z1[0]), ex2(z1[1]));                                  \
    P0.u[3] = cvtpk(ex2(z1[2]), ex2(z1[3]));                                  \
    P1.u[0] = cvtpk(ex2(z2[0]), ex2(z2[1]));                                  \
    P1.u[1] = cvtpk(ex2(z2[2]), ex2(z2[3]));                                  \
    P1.u[2] = cvtpk(ex2(z3[0]), ex2(z3[1]));                                  \
    P1.u[3] = cvtpk(ex2(z3[2]), ex2(z3[3]));                                  \
  }

  for (int it = 0; it < nIt; it++) {
    int cur = it & 1;
    __syncthreads();   // vmcnt(0) drain: K(it)+V(it) ready; prior reads done
    if (it + 1 < nIt) {
      int nb = cur ^ 1;
      GLD16(kp + ssw_k1,          &Kl[nb][(w * 16)     * 64]);
      GLD16(kp + 8 * DH + ssw_k2, &Kl[nb][(w * 16 + 8) * 64]);
      GLD16(vp,                   &Vl[nb][(w * 16)     * 64]);
      GLD16(vp + 8 * NSEQ,        &Vl[nb][(w * 16 + 8) * 64]);
      kp += 64 * DH; vp += 64;
    }

    // K fragments from LDS (permuted rows; 2-way bank aliasing = free)
    const unsigned short* Kb = &Kl[cur][0];
    bf16x8 k00 = ldb(&Kb[(krow0)      * 64 + swk0]);
    bf16x8 k01 = ldb(&Kb[(krow0)      * 64 + swk1]);
    bf16x8 k10 = ldb(&Kb[(krow0 + 4)  * 64 + swk0]);
    bf16x8 k11 = ldb(&Kb[(krow0 + 4)  * 64 + swk1]);
    bf16x8 k20 = ldb(&Kb[(krow0 + 32) * 64 + swk0]);
    bf16x8 k21 = ldb(&Kb[(krow0 + 32) * 64 + swk1]);
    bf16x8 k30 = ldb(&Kb[(krow0 + 36) * 64 + swk0]);
    bf16x8 k31 = ldb(&Kb[(krow0 + 36) * 64 + swk1]);

    // ---- QK: all 4 q-sets (scheduler free to overlap exp2 with MFMAs) ----
    QKSET(qa[0], qb[0], p0[0], p1[0]);
    QKSET(qa[1], qb[1], p0[1], p1[1]);
    QKSET(qa[2], qb[2], p0[2], p1[2]);
    QKSET(qa[3], qb[3], p0[3], p1[3]);

    // ---- PV: V fragments shared across all 4 q-sets ----
#pragma unroll
    for (int dt = 0; dt < 4; dt++) {
      bf16x8 v0 = ldb(&Vl[cur][(dt * 16 + c) * 64 + sw0]);
      bf16x8 v1 = ldb(&Vl[cur][(dt * 16 + c) * 64 + sw1]);
#pragma unroll
      for (int ss = 0; ss < 4; ss++) {
        acc[ss][dt] = mm(p0[ss].v, v0, acc[ss][dt]);
        acc[ss][dt] = mm(p1[ss].v, v1, acc[ss][dt]);
      }
    }
#pragma unroll
    for (int ss = 0; ss < 4; ss++) {
      accl[ss] = mm(p0[ss].v, ones, accl[ss]);
      accl[ss] = mm(p1[ss].v, ones, accl[ss]);
    }
  }
#undef QKSET

  size_t rb = ((size_t)(b * NH + h) * S + s) * NSEQ + i0 + w * 64;
#pragma unroll
  for (int ss = 0; ss < 4; ss++) {
    size_t rbs = rb + ss * 16;
    if (c == 0) {
#pragma unroll
      for (int rr = 0; rr < 4; rr++)
        lpart[rbs + quad * 4 + rr] = accl[ss][rr];
    }
#pragma unroll
    for (int rr = 0; rr < 4; rr++)
#pragma unroll
      for (int dt = 0; dt < 4; dt++)
        opart[(rbs + quad * 4 + rr) * 64 + dt * 16 + c] = f2bfr(acc[ss][dt][rr]);
  }
}

// ------ Kernel 3b: merge split-KV partials (plain sums) -> ao bf16 ----------
__global__ __launch_bounds__(256) void k_merge(
    const unsigned short* __restrict__ opart,
    const float* __restrict__ lpart,
    unsigned short* __restrict__ ao, int S) {
  int t = blockIdx.x * 256 + threadIdx.x;     // 131072 threads
  int row = t >> 2;                            // (b*NH+h)*NSEQ + i
  int dseg = (t & 3) * 16;
  int b = row >> 14, rem = row & 16383;
  int h = rem >> 12, i = rem & 4095;

  float l = 0.f;
  float o[16];
#pragma unroll
  for (int j = 0; j < 16; j++) o[j] = 0.f;
  for (int s = 0; s < S; s++) {
    size_t rb = ((size_t)(b * NH + h) * S + s) * NSEQ + i;
    l += lpart[rb];
    const unsigned short* p = opart + rb * 64 + dseg;
    u16x8 v0 = *(const u16x8*)p;
    u16x8 v1 = *(const u16x8*)(p + 8);
#pragma unroll
    for (int j = 0; j < 8; j++) {
      o[j]     += bf2f(v0[j]);
      o[8 + j] += bf2f(v1[j]);
    }
  }
  float inv = 1.f / l;
  unsigned short* dst = ao + ((size_t)b * NSEQ + i) * INNER + h * 64 + dseg;
  uint4 pk0 = { pack2(o[0] * inv, o[1] * inv),  pack2(o[2] * inv, o[3] * inv),
                pack2(o[4] * inv, o[5] * inv),  pack2(o[6] * inv, o[7] * inv) };
  uint4 pk1 = { pack2(o[8] * inv, o[9] * inv),  pack2(o[10] * inv, o[11] * inv),
                pack2(o[12] * inv, o[13] * inv),pack2(o[14] * inv, o[15] * inv) };
  *(uint4*)dst = pk0;
  *(uint4*)(dst + 8) = pk1;
}

// ------ Kernel 4: out-proj + residual, BK=128 (3 barriers total) ------------
__global__ __launch_bounds__(256) void k_out(const unsigned short* __restrict__ wob,
                                             const unsigned short* __restrict__ ao,
                                             const float* __restrict__ x,
                                             float* __restrict__ out) {
  int n0 = blockIdx.x * 64;
  int o0 = blockIdx.y * 64;
  int b  = blockIdx.z;
  __shared__ unsigned short Al[64 * 128];
  __shared__ unsigned short Bl[64 * 128];
  int t = threadIdx.x;
  int lane = t & 63, w = t >> 6;
  int c = lane & 15, quad = lane >> 4;
  int wm = w >> 1, wn = w & 1;
  f32x4 acc[2][2] = {};
  int lr = lane >> 4;
  int lchk = lane & 15;
  const unsigned short* apg = wob + (size_t)o0 * INNER;
  const unsigned short* bpg = ao + ((size_t)b * NSEQ + n0) * INNER;
  for (int kt = 0; kt < 2; kt++) {
    if (kt) __syncthreads();
#pragma unroll
    for (int q = 0; q < 4; q++) {
      int r = w * 16 + q * 4 + lr;
      int srcoff = r * INNER + kt * 128 + ((lchk ^ (r & 7)) * 8);
      GLD16(apg + srcoff, Al + (size_t)(w * 16 + q * 4) * 128);
      GLD16(bpg + srcoff, Bl + (size_t)(w * 16 + q * 4) * 128);
    }
    __syncthreads();
#pragma unroll
    for (int ks = 0; ks < 4; ks++) {
      int ra0 = wm * 32 + c, ra1 = ra0 + 16;
      int rb0 = wn * 32 + c, rb1 = rb0 + 16;
      bf16x8 a0 = ldb(&Al[ra0 * 128 + (((ks * 4 + quad) ^ (ra0 & 7)) * 8)]);
      bf16x8 a1 = ldb(&Al[ra1 * 128 + (((ks * 4 + quad) ^ (ra1 & 7)) * 8)]);
      bf16x8 b0 = ldb(&Bl[rb0 * 128 + (((ks * 4 + quad) ^ (rb0 & 7)) * 8)]);
      bf16x8 b1 = ldb(&Bl[rb1 * 128 + (((ks * 4 + quad) ^ (rb1 & 7)) * 8)]);
      acc[0][0] = mm(a0, b0, acc[0][0]);
      acc[0][1] = mm(a0, b1, acc[0][1]);
      acc[1][0] = mm(a1, b0, acc[1][0]);
      acc[1][1] = mm(a1, b1, acc[1][1]);
    }
  }
#pragma unroll
  for (int i = 0; i < 2; i++)
#pragma unroll
    for (int j = 0; j < 2; j++)
#pragma unroll
      for (int rr = 0; rr < 4; rr++) {
        int o = o0 + wm * 32 + i * 16 + quad * 4 + rr;
        int n = n0 + wn * 32 + j * 16 + c;
        size_t idx = ((size_t)b * CCH + o) * NSEQ + n;
        out[idx] = acc[i][j][rr] + x[idx];
      }
}

extern "C" void kernel_launch(void* const* d_in, const int* in_sizes, int n_in,
                              void* d_out, int out_size, void* d_ws, size_t ws_size,
                              hipStream_t stream) {
  const float* x     = (const float*)d_in[0];
  const float* gamma = (const float*)d_in[1];
  const float* wq    = (const float*)d_in[2];
  const float* wo    = (const float*)d_in[3];
  float* out = (float*)d_out;

  const size_t MB = 1u << 20;
  char* ws = (char*)d_ws;
  // ws layout:
  unsigned short* ao  = (unsigned short*)ws;                   // [0,4)  bf16 [B][N][256]
  unsigned short* xn  = (unsigned short*)(ws + 4 * MB);        // [4,8)  bf16 [B][N][256]
  unsigned short* qkv = (unsigned short*)(ws + 8 * MB);        // [8,20) bf16 [B][768][N] (v region used)
  unsigned short* wqb = (unsigned short*)(ws + 20 * MB);       // 384 KB
  unsigned short* wob = (unsigned short*)(ws + 20 * MB + 512 * 1024); // 128 KB
  unsigned short* qt  = (unsigned short*)(ws + 21 * MB);       // [21,25) bf16 [B][H][N][D]
  unsigned short* ktb = (unsigned short*)(ws + 25 * MB);       // [25,29) bf16 [B][H][N][D]
  unsigned short* opart = (unsigned short*)(ws + 29 * MB);     // S*B*H*N*64 bf16
  int S;
  if (ws_size >= 48 * MB) S = 4;
  else if (ws_size >= 40 * MB) S = 2;
  else S = 1;
  size_t opart_bytes = (size_t)S * BATCH * NH * NSEQ * DH * 2;
  float* lpart = (float*)(ws + 29 * MB + opart_bytes);
  int kvlen = NSEQ / S;

  k_lncvt<<<dim3(512),          256, 0, stream>>>(x, gamma, xn, wq, wo, wqb, wob);
  k_qkv  <<<dim3(64, 12, 2),    256, 0, stream>>>(wqb, xn, qkv, qt, ktb);
  k_attn <<<dim3(16, 4, 2 * S), 256, 0, stream>>>(qt, ktb, qkv, opart,
                                                  lpart, S, kvlen);
  k_merge<<<dim3(512),          256, 0, stream>>>(opart, lpart, ao, S);
  k_out  <<<dim3(64, 4, 2),     256, 0, stream>>>(wob, ao, x, out);
}